// Round 2
// baseline (127.993 us; speedup 1.0000x reference)
//
#include <hip/hip_runtime.h>
#include <math.h>

// One wave (64 lanes) per batch row; 256-thread block = 4 independent rows.
// Lane t owns atoms [16t, 16t+16) as 4 groups of 4 atoms (3 float4 each).
// Groups entirely past num_atoms skip their loads (saves ~50% HBM traffic on
// average since num_atoms ~ U[8,1024]).
__global__ __launch_bounds__(256) void rmsd_kernel(
    const float* __restrict__ inp, const float* __restrict__ tgt,
    const int* __restrict__ natoms, float* __restrict__ out, int batch)
{
    const int wave = threadIdx.x >> 6;
    const int lane = threadIdx.x & 63;
    const int b = blockIdx.x * 4 + wave;
    if (b >= batch) return;
    const int n = natoms[b];

    const float4* __restrict__ x4 = (const float4*)(inp + (size_t)b * 3072);
    const float4* __restrict__ y4 = (const float4*)(tgt + (size_t)b * 3072);

    // acc: 0-2 sum x, 3-5 sum y, 6-14 sum x_i*y_j, 15 sum|x|^2 + sum|y|^2
    float acc[16];
#pragma unroll
    for (int i = 0; i < 16; ++i) acc[i] = 0.f;

#pragma unroll
    for (int g = 0; g < 4; ++g) {
        const int a0 = lane * 16 + g * 4;   // first atom of this group
        if (a0 < n) {
            const int f = lane * 12 + g * 3; // float4 index within the row
            const float4 xa = x4[f], xb = x4[f + 1], xc = x4[f + 2];
            const float4 ya = y4[f], yb = y4[f + 1], yc = y4[f + 2];
            const float X[4][3] = {{xa.x,xa.y,xa.z},{xa.w,xb.x,xb.y},
                                   {xb.z,xb.w,xc.x},{xc.y,xc.z,xc.w}};
            const float Y[4][3] = {{ya.x,ya.y,ya.z},{ya.w,yb.x,yb.y},
                                   {yb.z,yb.w,yc.x},{yc.y,yc.z,yc.w}};
#pragma unroll
            for (int j = 0; j < 4; ++j) {
                const float m = (a0 + j < n) ? 1.f : 0.f;
                const float x0 = X[j][0]*m, x1 = X[j][1]*m, x2 = X[j][2]*m;
                const float y0 = Y[j][0]*m, y1 = Y[j][1]*m, y2 = Y[j][2]*m;
                acc[0] += x0; acc[1] += x1; acc[2] += x2;
                acc[3] += y0; acc[4] += y1; acc[5] += y2;
                acc[6]  += x0*y0; acc[7]  += x0*y1; acc[8]  += x0*y2;
                acc[9]  += x1*y0; acc[10] += x1*y1; acc[11] += x1*y2;
                acc[12] += x2*y0; acc[13] += x2*y1; acc[14] += x2*y2;
                acc[15] += x0*x0 + x1*x1 + x2*x2 + y0*y0 + y1*y1 + y2*y2;
            }
        }
    }

    // wave-wide butterfly reduction (all 16 accumulators)
#pragma unroll
    for (int o = 32; o > 0; o >>= 1) {
#pragma unroll
        for (int i = 0; i < 16; ++i) acc[i] += __shfl_xor(acc[i], o, 64);
    }

    if (lane == 0) {
        double s[16];
#pragma unroll
        for (int i = 0; i < 16; ++i) s[i] = (double)acc[i];
        const double nd = (double)n;

        // centered covariance R[i][j] = sum x_i y_j - (sum x_i)(sum y_j)/n
        double R[3][3];
        for (int i = 0; i < 3; ++i)
            for (int j = 0; j < 3; ++j)
                R[i][j] = s[6 + i*3 + j] - s[i] * s[3 + j] / nd;
        // e_x + e_y = (sum|x|^2 + sum|y|^2) - (|sum x|^2 + |sum y|^2)/n
        const double exy = s[15] - (s[0]*s[0] + s[1]*s[1] + s[2]*s[2]
                                  + s[3]*s[3] + s[4]*s[4] + s[5]*s[5]) / nd;

        const double detR =
              R[0][0]*(R[1][1]*R[2][2] - R[1][2]*R[2][1])
            - R[0][1]*(R[1][0]*R[2][2] - R[1][2]*R[2][0])
            + R[0][2]*(R[1][0]*R[2][1] - R[1][1]*R[2][0]);

        // K = R^T R (symmetric PSD); eigenvalues = squared singular values
        double K00=0, K01=0, K02=0, K11=0, K12=0, K22=0;
        for (int k = 0; k < 3; ++k) {
            K00 += R[k][0]*R[k][0]; K01 += R[k][0]*R[k][1]; K02 += R[k][0]*R[k][2];
            K11 += R[k][1]*R[k][1]; K12 += R[k][1]*R[k][2]; K22 += R[k][2]*R[k][2];
        }

        // analytic symmetric 3x3 eigenvalues (trig method), f64
        const double qm = (K00 + K11 + K22) / 3.0;
        const double p1 = K01*K01 + K02*K02 + K12*K12;
        const double p2 = (K00-qm)*(K00-qm) + (K11-qm)*(K11-qm)
                        + (K22-qm)*(K22-qm) + 2.0*p1;
        double e1, e2, e3;
        if (p2 <= 1e-30) {
            e1 = e2 = e3 = qm;
        } else {
            const double p = sqrt(p2 / 6.0);
            const double inv = 1.0 / p;
            const double B00 = (K00-qm)*inv, B11 = (K11-qm)*inv, B22 = (K22-qm)*inv;
            const double B01 = K01*inv, B02 = K02*inv, B12 = K12*inv;
            const double detB =
                  B00*(B11*B22 - B12*B12)
                - B01*(B01*B22 - B12*B02)
                + B02*(B01*B12 - B11*B02);
            double r = detB * 0.5;
            r = fmin(1.0, fmax(-1.0, r));
            const double phi = acos(r) / 3.0;
            e1 = qm + 2.0*p*cos(phi);
            e3 = qm + 2.0*p*cos(phi + 2.0943951023931953);  // smallest
            e2 = 3.0*qm - e1 - e3;
        }
        const double S1 = sqrt(fmax(e1, 0.0));
        const double S2 = sqrt(fmax(e2, 0.0));
        const double S3 = sqrt(fmax(e3, 0.0));
        const double dsg = (detR < 0.0) ? -1.0 : 1.0;  // detR==0 => S3==0
        const double sv = S1 + S2 + dsg * S3;

        const double e = exy - 2.0 * sv;
        out[b] = (float)sqrt(fmax(e / nd, 1e-12));
    }
}

extern "C" void kernel_launch(void* const* d_in, const int* in_sizes, int n_in,
                              void* d_out, int out_size, void* d_ws, size_t ws_size,
                              hipStream_t stream) {
    const float* inp = (const float*)d_in[0];
    const float* tgt = (const float*)d_in[1];
    const int*   na  = (const int*)d_in[2];
    float* out = (float*)d_out;
    const int batch = in_sizes[2];  // 4096
    rmsd_kernel<<<(batch + 3) / 4, 256, 0, stream>>>(inp, tgt, na, out, batch);
}

// Round 3
// 123.374 us; speedup vs baseline: 1.0374x; 1.0374x over previous
//
#include <hip/hip_runtime.h>
#include <math.h>

// One wave (64 lanes) per batch row; 256-thread block = 4 independent rows.
// Lane t owns atoms [16t, 16t+16) as 2 groups of 8 atoms (6 float4 each).
// Groups entirely past num_atoms skip their loads (~50% HBM traffic saved on
// average, num_atoms ~ U[8,1024]); fully-interior groups skip mask math.
__global__ __launch_bounds__(256) void rmsd_kernel(
    const float* __restrict__ inp, const float* __restrict__ tgt,
    const int* __restrict__ natoms, float* __restrict__ out, int batch)
{
    const int wave = threadIdx.x >> 6;
    const int lane = threadIdx.x & 63;
    const int b = blockIdx.x * 4 + wave;
    if (b >= batch) return;
    const int n = natoms[b];

    const float4* __restrict__ x4 = (const float4*)(inp + (size_t)b * 3072);
    const float4* __restrict__ y4 = (const float4*)(tgt + (size_t)b * 3072);

    // acc: 0-2 sum x, 3-5 sum y, 6-14 sum x_i*y_j, 15 sum|x|^2 + sum|y|^2
    float acc[16];
#pragma unroll
    for (int i = 0; i < 16; ++i) acc[i] = 0.f;

#pragma unroll
    for (int g = 0; g < 2; ++g) {
        const int a0 = lane * 16 + g * 8;    // first atom of this 8-atom group
        if (a0 < n) {
            const int f = lane * 12 + g * 6; // float4 index within the row
            float4 xv[6], yv[6];
#pragma unroll
            for (int k = 0; k < 6; ++k) { xv[k] = x4[f + k]; yv[k] = y4[f + k]; }
            const float* X = (const float*)xv;
            const float* Y = (const float*)yv;
            if (a0 + 8 <= n) {
                // fully interior: no masking
#pragma unroll
                for (int j = 0; j < 8; ++j) {
                    const float x0 = X[j*3], x1 = X[j*3+1], x2 = X[j*3+2];
                    const float y0 = Y[j*3], y1 = Y[j*3+1], y2 = Y[j*3+2];
                    acc[0] += x0; acc[1] += x1; acc[2] += x2;
                    acc[3] += y0; acc[4] += y1; acc[5] += y2;
                    acc[6]  += x0*y0; acc[7]  += x0*y1; acc[8]  += x0*y2;
                    acc[9]  += x1*y0; acc[10] += x1*y1; acc[11] += x1*y2;
                    acc[12] += x2*y0; acc[13] += x2*y1; acc[14] += x2*y2;
                    acc[15] += x0*x0 + x1*x1 + x2*x2 + y0*y0 + y1*y1 + y2*y2;
                }
            } else {
#pragma unroll
                for (int j = 0; j < 8; ++j) {
                    const float m = (a0 + j < n) ? 1.f : 0.f;
                    const float x0 = X[j*3]*m, x1 = X[j*3+1]*m, x2 = X[j*3+2]*m;
                    const float y0 = Y[j*3]*m, y1 = Y[j*3+1]*m, y2 = Y[j*3+2]*m;
                    acc[0] += x0; acc[1] += x1; acc[2] += x2;
                    acc[3] += y0; acc[4] += y1; acc[5] += y2;
                    acc[6]  += x0*y0; acc[7]  += x0*y1; acc[8]  += x0*y2;
                    acc[9]  += x1*y0; acc[10] += x1*y1; acc[11] += x1*y2;
                    acc[12] += x2*y0; acc[13] += x2*y1; acc[14] += x2*y2;
                    acc[15] += x0*x0 + x1*x1 + x2*x2 + y0*y0 + y1*y1 + y2*y2;
                }
            }
        }
    }

    // wave-wide butterfly reduction (all 16 accumulators)
#pragma unroll
    for (int o = 32; o > 0; o >>= 1) {
#pragma unroll
        for (int i = 0; i < 16; ++i) acc[i] += __shfl_xor(acc[i], o, 64);
    }

    if (lane == 0) {
        double s[16];
#pragma unroll
        for (int i = 0; i < 16; ++i) s[i] = (double)acc[i];
        const double nd = (double)n;

        // centered covariance R[i][j] = sum x_i y_j - (sum x_i)(sum y_j)/n
        double R[3][3];
        for (int i = 0; i < 3; ++i)
            for (int j = 0; j < 3; ++j)
                R[i][j] = s[6 + i*3 + j] - s[i] * s[3 + j] / nd;
        // e_x + e_y = (sum|x|^2 + sum|y|^2) - (|sum x|^2 + |sum y|^2)/n
        const double exy = s[15] - (s[0]*s[0] + s[1]*s[1] + s[2]*s[2]
                                  + s[3]*s[3] + s[4]*s[4] + s[5]*s[5]) / nd;

        const double detR =
              R[0][0]*(R[1][1]*R[2][2] - R[1][2]*R[2][1])
            - R[0][1]*(R[1][0]*R[2][2] - R[1][2]*R[2][0])
            + R[0][2]*(R[1][0]*R[2][1] - R[1][1]*R[2][0]);

        // K = R^T R (symmetric PSD); eigenvalues = squared singular values
        double K00=0, K01=0, K02=0, K11=0, K12=0, K22=0;
        for (int k = 0; k < 3; ++k) {
            K00 += R[k][0]*R[k][0]; K01 += R[k][0]*R[k][1]; K02 += R[k][0]*R[k][2];
            K11 += R[k][1]*R[k][1]; K12 += R[k][1]*R[k][2]; K22 += R[k][2]*R[k][2];
        }

        // analytic symmetric 3x3 eigenvalues (trig method), f64
        const double qm = (K00 + K11 + K22) / 3.0;
        const double p1 = K01*K01 + K02*K02 + K12*K12;
        const double p2 = (K00-qm)*(K00-qm) + (K11-qm)*(K11-qm)
                        + (K22-qm)*(K22-qm) + 2.0*p1;
        double e1, e2, e3;
        if (p2 <= 1e-30) {
            e1 = e2 = e3 = qm;
        } else {
            const double p = sqrt(p2 / 6.0);
            const double inv = 1.0 / p;
            const double B00 = (K00-qm)*inv, B11 = (K11-qm)*inv, B22 = (K22-qm)*inv;
            const double B01 = K01*inv, B02 = K02*inv, B12 = K12*inv;
            const double detB =
                  B00*(B11*B22 - B12*B12)
                - B01*(B01*B22 - B12*B02)
                + B02*(B01*B12 - B11*B02);
            double r = detB * 0.5;
            r = fmin(1.0, fmax(-1.0, r));
            const double phi = acos(r) / 3.0;
            e1 = qm + 2.0*p*cos(phi);
            e3 = qm + 2.0*p*cos(phi + 2.0943951023931953);  // smallest
            e2 = 3.0*qm - e1 - e3;
        }
        const double S1 = sqrt(fmax(e1, 0.0));
        const double S2 = sqrt(fmax(e2, 0.0));
        const double S3 = sqrt(fmax(e3, 0.0));
        const double dsg = (detR < 0.0) ? -1.0 : 1.0;  // detR==0 => S3==0
        const double sv = S1 + S2 + dsg * S3;

        const double e = exy - 2.0 * sv;
        out[b] = (float)sqrt(fmax(e / nd, 1e-12));
    }
}

extern "C" void kernel_launch(void* const* d_in, const int* in_sizes, int n_in,
                              void* d_out, int out_size, void* d_ws, size_t ws_size,
                              hipStream_t stream) {
    const float* inp = (const float*)d_in[0];
    const float* tgt = (const float*)d_in[1];
    const int*   na  = (const int*)d_in[2];
    float* out = (float*)d_out;
    const int batch = in_sizes[2];  // 4096
    rmsd_kernel<<<(batch + 3) / 4, 256, 0, stream>>>(inp, tgt, na, out, batch);
}